// Round 3
// baseline (284.245 us; speedup 1.0000x reference)
//
#include <hip/hip_runtime.h>
#include <stdint.h>

typedef unsigned int u32;
typedef unsigned long long u64;

#define BATCH 16
#define NANCH 25200
#define NCLS 80
#define ROWF 85
#define MAXC 1000
#define CONF_T 0.25f
#define IOU_T 0.45f
#define EPS_F 1e-7f
#define TILE 64                  /* anchors per block in k1 */
#define NTILES ((NANCH + TILE - 1) / TILE)   /* 394, last tile = 48 */

// IoU exactly as the numpy/JAX reference computes it (no FMA contraction:
// keep inter's rounding separate from the union subtraction).
__device__ __forceinline__ float iou_ref(float4 a, float4 b) {
#pragma clang fp contract(off)
  float ai = (a.z - a.x) * (a.w - a.y);
  float aj = (b.z - b.x) * (b.w - b.y);
  float ltx = fmaxf(a.x, b.x), lty = fmaxf(a.y, b.y);
  float rbx = fminf(a.z, b.z), rby = fminf(a.w, b.w);
  float wx = fmaxf(rbx - ltx, 0.0f), wy = fmaxf(rby - lty, 0.0f);
  float inter = wx * wy;
  return inter / (ai + aj - inter + EPS_F);
}

// K1 (R3 rewrite): LDS-staged, fully coalesced scoring.
// Block = 256 threads = one 64-anchor tile of one batch. Stage 64x85 floats
// via 256-wide coalesced float4 loads -> LDS; 4 threads per anchor scan 20
// classes each; shfl_xor butterfly combine with exact first-max tie rule.
// key = ordered(score)<<32 | (32767-n)<<7 | cls  (desc score, ties asc index)
__global__ __launch_bounds__(256) void k1_score(const float* __restrict__ pred,
                                                u64* __restrict__ keys,
                                                u32* __restrict__ hist) {
  __shared__ float srow[TILE * ROWF];     // 21760 B
  __shared__ u64 skeys[TILE];
  __shared__ u32 lh[256];
  int tid = threadIdx.x;
  int b = blockIdx.y;
  int t0 = blockIdx.x * TILE;
  int ntile = (t0 + TILE <= NANCH) ? TILE : (NANCH - t0);   // 64 or 48
  int nf4 = (ntile * ROWF) >> 2;          // 1360 or 1020 (both exact)

  lh[tid] = 0;
  const float4* src4 = (const float4*)(pred + ((size_t)b * NANCH + t0) * ROWF);
  float4* smem4 = (float4*)srow;
#pragma unroll
  for (int k = 0; k < 6; ++k) {
    int i = k * 256 + tid;
    if (i < nf4) smem4[i] = src4[i];
  }
  __syncthreads();

  int a = tid >> 2;          // anchor in tile
  int q = tid & 3;           // class-quarter
  float best = -1e30f;
  int bidx = 0;
  float obj = 0.0f;
  if (a < ntile) {
    const float* row = srow + a * ROWF;
    obj = row[4];
    int c0 = q * 20;
#pragma unroll
    for (int c = 0; c < 20; ++c) {
      float s = row[5 + c0 + c] * obj;        // exact same mul as reference
      if (s > best) { best = s; bidx = c0 + c; }
    }
  }
  // butterfly combine across the 4 threads of this anchor (exact tie rule:
  // larger score wins; equal score -> lower class index wins)
#pragma unroll
  for (int off = 1; off < 4; off <<= 1) {
    float ob = __shfl_xor(best, off);
    int oi = __shfl_xor(bidx, off);
    if (ob > best || (ob == best && oi < bidx)) { best = ob; bidx = oi; }
  }
  if (q == 0 && a < ntile) {
    int n = t0 + a;
    bool valid = (obj > CONF_T) && (best > CONF_T);
    u32 hi;
    if (valid) hi = __float_as_uint(best) | 0x80000000u;  // ordered-float
    else hi = ((u32)n * 2654435761u) >> 1;                // spread, <0x80000000
    u32 lo = ((u32)(32767 - n) << 7) | (u32)bidx;
    skeys[a] = ((u64)hi << 32) | lo;
    atomicAdd(&lh[hi >> 24], 1u);
  }
  __syncthreads();
  if (tid < ntile) keys[(size_t)b * NANCH + t0 + tid] = skeys[tid];
  u32 v = lh[tid];
  if (v) atomicAdd(&hist[b * 256 + tid], v);
}

// K2: per-batch exact top-1000 (radix select on high 32 bits, compact,
// bitonic sort 2048 in LDS), gather boxes, build offset boxes.
__global__ __launch_bounds__(1024) void k2_select(const float* __restrict__ pred,
                                                  const u64* __restrict__ keys,
                                                  const u32* __restrict__ hist,
                                                  float* __restrict__ selbox,
                                                  float* __restrict__ offbox,
                                                  float* __restrict__ selconf,
                                                  float* __restrict__ selcls,
                                                  u32* __restrict__ selvalid) {
  int b = blockIdx.x;
  int tid = threadIdx.x;
  __shared__ u32 h[256];
  __shared__ u32 sh_sel;
  __shared__ int sh_rank;
  __shared__ u32 scount;
  __shared__ u64 skey[2048];

  const u32* hik = (const u32*)(keys + (size_t)b * NANCH);  // [2i+1] = high word
  u32 prefix = 0;
  for (int r = 0; r < 4; ++r) {
    if (r == 0) {
      if (tid < 256) h[tid] = hist[b * 256 + tid];
    } else {
      if (tid < 256) h[tid] = 0;
      __syncthreads();
      int shift = 24 - 8 * r;
      for (int i = tid; i < NANCH; i += 1024) {
        u32 hi = hik[2 * i + 1];
        if ((hi >> (shift + 8)) == prefix)
          atomicAdd(&h[(hi >> shift) & 255u], 1u);
      }
    }
    __syncthreads();
    if (tid < 64) {   // wave-0 parallel suffix-scan select, no barriers inside
      int l = tid;
      u32 a0 = h[4 * l + 0], a1 = h[4 * l + 1], a2 = h[4 * l + 2], a3 = h[4 * l + 3];
      u32 lane_sum = a0 + a1 + a2 + a3;
      u32 suf = lane_sum;
#pragma unroll
      for (int off = 1; off < 64; off <<= 1) {
        u32 tv = __shfl_down(suf, off);
        if (l + off < 64) suf += tv;
      }
      int rank = (r == 0) ? MAXC : sh_rank;
      u32 e3 = suf - lane_sum; u32 i3 = e3 + a3;
      u32 e2 = i3;             u32 i2 = e2 + a2;
      u32 e1 = i2;             u32 i1 = e1 + a1;
      u32 e0 = i1;             u32 i0 = e0 + a0;
      if ((int)i3 >= rank && (int)e3 < rank) { sh_sel = 4u * l + 3u; sh_rank = rank - (int)e3; }
      if ((int)i2 >= rank && (int)e2 < rank) { sh_sel = 4u * l + 2u; sh_rank = rank - (int)e2; }
      if ((int)i1 >= rank && (int)e1 < rank) { sh_sel = 4u * l + 1u; sh_rank = rank - (int)e1; }
      if ((int)i0 >= rank && (int)e0 < rank) { sh_sel = 4u * l + 0u; sh_rank = rank - (int)e0; }
    }
    __syncthreads();
    prefix = (r == 0) ? sh_sel : ((prefix << 8) | sh_sel);
  }
  u32 Cstar = prefix;

  if (tid == 0) scount = 0;
  skey[tid] = ~0ull;
  skey[tid + 1024] = ~0ull;
  __syncthreads();
  for (int i = tid; i < NANCH; i += 1024) {
    u64 k = keys[(size_t)b * NANCH + i];
    if ((u32)(k >> 32) >= Cstar) {
      u32 p = atomicAdd(&scount, 1u);
      if (p < 2048) skey[p] = ~k;      // sort ascending on ~key == descending key
    }
  }
  __syncthreads();
  for (u32 kk = 2; kk <= 2048; kk <<= 1) {
    for (u32 j = kk >> 1; j > 0; j >>= 1) {
      for (int idx = tid; idx < 2048; idx += 1024) {
        u32 ixj = (u32)idx ^ j;
        if (ixj > (u32)idx) {
          u64 a = skey[idx], c2 = skey[ixj];
          bool up = ((idx & kk) == 0);
          if (up ? (a > c2) : (a < c2)) { skey[idx] = c2; skey[ixj] = a; }
        }
      }
      __syncthreads();
    }
  }
  if (tid < MAXC) {
    u64 k = ~skey[tid];
    u32 hi = (u32)(k >> 32);
    u32 lo = (u32)k;
    u32 n = 32767u - (lo >> 7);
    u32 ci = lo & 127u;
    bool valid = hi > 0x80000000u;
    float conf = valid ? __uint_as_float(hi & 0x7FFFFFFFu) : 0.0f;
    const float* pr = pred + ((size_t)b * NANCH + n) * ROWF;
    float x = pr[0], y = pr[1], w = pr[2], h2 = pr[3];
    float x1 = x - w * 0.5f, y1 = y - h2 * 0.5f;
    float x2 = x + w * 0.5f, y2 = y + h2 * 0.5f;
    float cf = (float)ci;
    float off = cf * 4096.0f;
    int o4 = (b * MAXC + tid) * 4;
    selbox[o4 + 0] = x1; selbox[o4 + 1] = y1; selbox[o4 + 2] = x2; selbox[o4 + 3] = y2;
    offbox[o4 + 0] = x1 + off; offbox[o4 + 1] = y1 + off;
    offbox[o4 + 2] = x2 + off; offbox[o4 + 3] = y2 + off;
    selconf[b * MAXC + tid] = conf;
    selcls[b * MAXC + tid] = cf;
    selvalid[b * MAXC + tid] = valid ? 1u : 0u;
  }
}

// K3: TRANSPOSED suppression bit-matrix Dt. Row i (victim), bit j set iff
// iou(j,i) > T and j < i. One wave per row; ballot -> u64 words.
__global__ __launch_bounds__(256) void k3_dt(const float4* __restrict__ offbox4,
                                             u64* __restrict__ dt) {
  int wid = blockIdx.x * 4 + (threadIdx.x >> 6);   // b*MAXC + i
  int lane = threadIdx.x & 63;
  int b = wid / MAXC;
  int i = wid % MAXC;
  float4 bi = offbox4[b * MAXC + i];
  u64 myword = 0;
  for (int w = 0; w < 16; ++w) {
    int j = w * 64 + lane;
    int jc = (j < MAXC) ? j : 0;
    float4 bj = offbox4[b * MAXC + jc];
    float iou = iou_ref(bi, bj);
    bool bit = (iou > IOU_T) && (j < i);            // j<i implies j<MAXC
    u64 bal = __ballot(bit ? 1 : 0);
    if (lane == w) myword = bal;
  }
  if (lane < 16) dt[((size_t)b * MAXC + i) * 16 + lane] = myword;
}

// K4: Jacobi fixed-point of keep[i] = valid[i] & ~OR_{j<i}(keep[j]&D[j,i]).
// Unique fixed point == greedy NMS result; converges in max-chain-depth
// passes (~2-5 for random boxes). Thread i holds Dt row in registers;
// keep vector (16 u64) lives in LDS, rebuilt per pass via per-wave ballots.
__global__ __launch_bounds__(1024) void k4_jacobi(const u64* __restrict__ dt,
                                                  const u32* __restrict__ selvalid,
                                                  const float* __restrict__ selbox,
                                                  const float* __restrict__ selconf,
                                                  const float* __restrict__ selcls,
                                                  float* __restrict__ out) {
  int b = blockIdx.x;
  int tid = threadIdx.x;
  int wv = tid >> 6, lane = tid & 63;
  __shared__ u64 keepv[16];
  __shared__ u32 changed;
  bool valid = false;
  u64 dtr[16];
  if (tid < MAXC) {
    valid = selvalid[b * MAXC + tid] != 0u;
#pragma unroll
    for (int w = 0; w < 16; ++w) dtr[w] = dt[((size_t)b * MAXC + tid) * 16 + w];
  } else {
#pragma unroll
    for (int w = 0; w < 16; ++w) dtr[w] = 0ull;
  }
  u64 bal0 = __ballot(valid ? 1 : 0);
  if (tid == 0) changed = 0;
  if (lane == 0) keepv[wv] = bal0;
  __syncthreads();
  for (int pass = 0; pass < MAXC; ++pass) {
    u64 kv[16];
#pragma unroll
    for (int w = 0; w < 16; ++w) kv[w] = keepv[w];
    u64 s = 0;
#pragma unroll
    for (int w = 0; w < 16; ++w) s |= dtr[w] & kv[w];
    bool nk = valid && (s == 0ull);
    u64 bal = __ballot(nk ? 1 : 0);
    __syncthreads();                       // A: all keepv reads done
    if (lane == 0 && bal != kv[wv]) { keepv[wv] = bal; atomicOr(&changed, 1u); }
    __syncthreads();                       // B: writes visible
    u32 ch = changed;
    __syncthreads();                       // C: all read ch before reset
    if (tid == 0) changed = 0;
    if (!ch) break;                        // ch uniform -> uniform exit
  }
  // keepv stable (last pass wrote nothing), barriers already passed.
  if (tid < MAXC) {
    bool kept = ((keepv[wv] >> lane) & 1ull) != 0ull;
    size_t o = (size_t)b * MAXC + tid;
    const float4* sb4 = (const float4*)selbox;
    float4 bx = sb4[o];
    float cf = selconf[o], cl = selcls[o];
    float* orow = out + o * 6;
    orow[0] = kept ? bx.x : 0.0f;
    orow[1] = kept ? bx.y : 0.0f;
    orow[2] = kept ? bx.z : 0.0f;
    orow[3] = kept ? bx.w : 0.0f;
    orow[4] = kept ? cf : 0.0f;
    orow[5] = kept ? cl : 0.0f;
    out[(size_t)BATCH * MAXC * 6 + o] = kept ? 1.0f : 0.0f;
  }
}

extern "C" void kernel_launch(void* const* d_in, const int* in_sizes, int n_in,
                              void* d_out, int out_size, void* d_ws, size_t ws_size,
                              hipStream_t stream) {
  const float* pred = (const float*)d_in[0];
  float* out = (float*)d_out;
  char* ws = (char*)d_ws;
  size_t off = 0;
  auto alloc = [&](size_t bytes) -> void* {
    void* p = ws + off;
    off = (off + bytes + 255) & ~(size_t)255;
    return p;
  };
  u64* keys     = (u64*)alloc((size_t)BATCH * NANCH * 8);
  u32* hist     = (u32*)alloc((size_t)BATCH * 256 * 4);
  float* selbox = (float*)alloc((size_t)BATCH * MAXC * 4 * 4);
  float* offbox = (float*)alloc((size_t)BATCH * MAXC * 4 * 4);
  float* selconf= (float*)alloc((size_t)BATCH * MAXC * 4);
  float* selcls = (float*)alloc((size_t)BATCH * MAXC * 4);
  u32* selvalid = (u32*)alloc((size_t)BATCH * MAXC * 4);
  u64* dt       = (u64*)alloc((size_t)BATCH * MAXC * 16 * 8);
  (void)ws_size; (void)in_sizes; (void)n_in; (void)out_size;

  hipMemsetAsync(hist, 0, (size_t)BATCH * 256 * 4, stream);

  dim3 g1(NTILES, BATCH);
  k1_score<<<g1, 256, 0, stream>>>(pred, keys, hist);
  k2_select<<<BATCH, 1024, 0, stream>>>(pred, keys, hist, selbox, offbox,
                                        selconf, selcls, selvalid);
  k3_dt<<<(BATCH * MAXC) / 4, 256, 0, stream>>>((const float4*)offbox, dt);
  k4_jacobi<<<BATCH, 1024, 0, stream>>>(dt, selvalid, selbox, selconf,
                                        selcls, out);
}

// Round 4
// 275.512 us; speedup vs baseline: 1.0317x; 1.0317x over previous
//
#include <hip/hip_runtime.h>
#include <stdint.h>

typedef unsigned int u32;
typedef unsigned long long u64;

#define BATCH 16
#define NANCH 25200
#define NCLS 80
#define ROWF 85
#define MAXC 1000
#define CONF_T 0.25f
#define IOU_T 0.45f
#define EPS_F 1e-7f
#define TILE 64
#define NTILES ((NANCH + TILE - 1) / TILE)   /* 394, last tile = 48 */

// IoU exactly as the numpy/JAX reference computes it (no FMA contraction:
// keep inter's rounding separate from the union subtraction).
__device__ __forceinline__ float iou_ref(float4 a, float4 b) {
#pragma clang fp contract(off)
  float ai = (a.z - a.x) * (a.w - a.y);
  float aj = (b.z - b.x) * (b.w - b.y);
  float ltx = fmaxf(a.x, b.x), lty = fmaxf(a.y, b.y);
  float rbx = fminf(a.z, b.z), rby = fminf(a.w, b.w);
  float wx = fmaxf(rbx - ltx, 0.0f), wy = fmaxf(rby - lty, 0.0f);
  float inter = wx * wy;
  return inter / (ai + aj - inter + EPS_F);
}

// K1: LDS-staged coalesced scoring (BW-bound, ~25 us; unchanged from R3).
// key = ordered(score)<<32 | (32767-n)<<7 | cls  (desc score, ties asc index)
__global__ __launch_bounds__(256) void k1_score(const float* __restrict__ pred,
                                                u64* __restrict__ keys,
                                                u32* __restrict__ hist) {
  __shared__ float srow[TILE * ROWF];     // 21760 B
  __shared__ u64 skeys[TILE];
  __shared__ u32 lh[256];
  int tid = threadIdx.x;
  int b = blockIdx.y;
  int t0 = blockIdx.x * TILE;
  int ntile = (t0 + TILE <= NANCH) ? TILE : (NANCH - t0);   // 64 or 48
  int nf4 = (ntile * ROWF) >> 2;          // 1360 or 1020 (both exact)

  lh[tid] = 0;
  const float4* src4 = (const float4*)(pred + ((size_t)b * NANCH + t0) * ROWF);
  float4* smem4 = (float4*)srow;
#pragma unroll
  for (int k = 0; k < 6; ++k) {
    int i = k * 256 + tid;
    if (i < nf4) smem4[i] = src4[i];
  }
  __syncthreads();

  int a = tid >> 2;          // anchor in tile
  int q = tid & 3;           // class-quarter
  float best = -1e30f;
  int bidx = 0;
  float obj = 0.0f;
  if (a < ntile) {
    const float* row = srow + a * ROWF;
    obj = row[4];
    int c0 = q * 20;
#pragma unroll
    for (int c = 0; c < 20; ++c) {
      float s = row[5 + c0 + c] * obj;        // exact same mul as reference
      if (s > best) { best = s; bidx = c0 + c; }
    }
  }
  // exact tie rule: larger score wins; equal score -> lower class index wins
#pragma unroll
  for (int off = 1; off < 4; off <<= 1) {
    float ob = __shfl_xor(best, off);
    int oi = __shfl_xor(bidx, off);
    if (ob > best || (ob == best && oi < bidx)) { best = ob; bidx = oi; }
  }
  if (q == 0 && a < ntile) {
    int n = t0 + a;
    bool valid = (obj > CONF_T) && (best > CONF_T);
    u32 hi;
    if (valid) hi = __float_as_uint(best) | 0x80000000u;  // ordered-float
    else hi = ((u32)n * 2654435761u) >> 1;                // spread, <0x80000000
    u32 lo = ((u32)(32767 - n) << 7) | (u32)bidx;
    skeys[a] = ((u64)hi << 32) | lo;
    atomicAdd(&lh[hi >> 24], 1u);
  }
  __syncthreads();
  if (tid < ntile) keys[(size_t)b * NANCH + t0 + tid] = skeys[tid];
  u32 v = lh[tid];
  if (v) atomicAdd(&hist[b * 256 + tid], v);
}

// K2 (R4): exact top-1000. Radix rounds 8+12+12 bits (2 refine scans, not 3),
// MLP-4 coalesced u64 scan loops, two-level suffix-scan bin select,
// compact, bitonic 2048, gather epilogue.
__global__ __launch_bounds__(1024) void k2_select(const float* __restrict__ pred,
                                                  const u64* __restrict__ keys,
                                                  const u32* __restrict__ hist,
                                                  float* __restrict__ selbox,
                                                  float* __restrict__ offbox,
                                                  float* __restrict__ selconf,
                                                  float* __restrict__ selcls,
                                                  u32* __restrict__ selvalid) {
  int b = blockIdx.x;
  int tid = threadIdx.x;
  int wv = tid >> 6, lane = tid & 63;
  __shared__ u32 h4[4096];
  __shared__ u32 wsum[16];
  __shared__ u32 sh_sel;
  __shared__ int sh_rank;
  __shared__ u32 scount;
  __shared__ u64 skey[2048];

  const u64* kb = keys + (size_t)b * NANCH;

  // ---- round 0: 8-bit bins from k1's histogram (wave 0 only) ----
  if (tid < 256) h4[tid] = hist[b * 256 + tid];
  __syncthreads();
  if (tid < 64) {
    int l = tid;
    u32 a0 = h4[4 * l], a1 = h4[4 * l + 1], a2 = h4[4 * l + 2], a3 = h4[4 * l + 3];
    u32 lsum = a0 + a1 + a2 + a3;
    u32 suf = lsum;
#pragma unroll
    for (int off = 1; off < 64; off <<= 1) {
      u32 tv = __shfl_down(suf, off);
      if (l + off < 64) suf += tv;
    }
    int rank = MAXC;
    u32 e3 = suf - lsum; u32 i3 = e3 + a3;
    u32 e2 = i3;         u32 i2 = e2 + a2;
    u32 e1 = i2;         u32 i1 = e1 + a1;
    u32 e0 = i1;         u32 i0 = e0 + a0;
    if ((int)i3 >= rank && (int)e3 < rank) { sh_sel = 4u*l+3u; sh_rank = rank-(int)e3; }
    if ((int)i2 >= rank && (int)e2 < rank) { sh_sel = 4u*l+2u; sh_rank = rank-(int)e2; }
    if ((int)i1 >= rank && (int)e1 < rank) { sh_sel = 4u*l+1u; sh_rank = rank-(int)e1; }
    if ((int)i0 >= rank && (int)e0 < rank) { sh_sel = 4u*l+0u; sh_rank = rank-(int)e0; }
  }
  __syncthreads();
  u32 prefix = sh_sel;   // 8 bits

  // ---- rounds A,B: 12-bit bins, all 16 waves ----
#pragma unroll
  for (int r = 0; r < 2; ++r) {
    for (int i = tid; i < 4096; i += 1024) h4[i] = 0;
    __syncthreads();
    int psh = (r == 0) ? 24 : 12;     // prefix compare shift
    int bsh = (r == 0) ? 12 : 0;      // bin extract shift
    for (int i0 = tid; i0 < NANCH; i0 += 4096) {
      int j1 = i0 + 1024, j2 = i0 + 2048, j3 = i0 + 3072;
      u64 k0 = kb[i0];
      u64 k1v = (j1 < NANCH) ? kb[j1] : 0;
      u64 k2v = (j2 < NANCH) ? kb[j2] : 0;
      u64 k3v = (j3 < NANCH) ? kb[j3] : 0;
      u32 h0 = (u32)(k0 >> 32), h1 = (u32)(k1v >> 32);
      u32 h2 = (u32)(k2v >> 32), h3 = (u32)(k3v >> 32);
      if ((h0 >> psh) == prefix) atomicAdd(&h4[(h0 >> bsh) & 0xFFFu], 1u);
      if (j1 < NANCH && (h1 >> psh) == prefix) atomicAdd(&h4[(h1 >> bsh) & 0xFFFu], 1u);
      if (j2 < NANCH && (h2 >> psh) == prefix) atomicAdd(&h4[(h2 >> bsh) & 0xFFFu], 1u);
      if (j3 < NANCH && (h3 >> psh) == prefix) atomicAdd(&h4[(h3 >> bsh) & 0xFFFu], 1u);
    }
    __syncthreads();
    // two-level suffix select over 4096 bins; thread t owns bins 4t..4t+3
    u32 a0 = h4[4 * tid], a1 = h4[4 * tid + 1], a2 = h4[4 * tid + 2], a3 = h4[4 * tid + 3];
    u32 lsum = a0 + a1 + a2 + a3;
    u32 suf = lsum;
#pragma unroll
    for (int off = 1; off < 64; off <<= 1) {
      u32 tv = __shfl_down(suf, off);
      if (lane + off < 64) suf += tv;
    }
    if (lane == 0) wsum[wv] = suf;
    int rank = sh_rank;               // read BEFORE any writer can update
    __syncthreads();
    u32 base = 0;
#pragma unroll
    for (int w2 = 0; w2 < 16; ++w2) if (w2 > wv) base += wsum[w2];
    u32 e3 = base + suf - lsum; u32 i3 = e3 + a3;
    u32 e2 = i3;                u32 i2 = e2 + a2;
    u32 e1 = i2;                u32 i1 = e1 + a1;
    u32 e0 = i1;                u32 i0 = e0 + a0;
    if ((int)i3 >= rank && (int)e3 < rank) { sh_sel = 4u*tid+3u; sh_rank = rank-(int)e3; }
    if ((int)i2 >= rank && (int)e2 < rank) { sh_sel = 4u*tid+2u; sh_rank = rank-(int)e2; }
    if ((int)i1 >= rank && (int)e1 < rank) { sh_sel = 4u*tid+1u; sh_rank = rank-(int)e1; }
    if ((int)i0 >= rank && (int)e0 < rank) { sh_sel = 4u*tid+0u; sh_rank = rank-(int)e0; }
    __syncthreads();
    prefix = (prefix << 12) | sh_sel;
  }
  u32 Cstar = prefix;

  // ---- compact (MLP-4) ----
  if (tid == 0) scount = 0;
  skey[tid] = ~0ull;
  skey[tid + 1024] = ~0ull;
  __syncthreads();
  for (int i0 = tid; i0 < NANCH; i0 += 4096) {
    int j1 = i0 + 1024, j2 = i0 + 2048, j3 = i0 + 3072;
    u64 k0 = kb[i0];
    u64 k1v = (j1 < NANCH) ? kb[j1] : 0;
    u64 k2v = (j2 < NANCH) ? kb[j2] : 0;
    u64 k3v = (j3 < NANCH) ? kb[j3] : 0;
    if ((u32)(k0 >> 32) >= Cstar) { u32 p = atomicAdd(&scount, 1u); if (p < 2048) skey[p] = ~k0; }
    if (j1 < NANCH && (u32)(k1v >> 32) >= Cstar) { u32 p = atomicAdd(&scount, 1u); if (p < 2048) skey[p] = ~k1v; }
    if (j2 < NANCH && (u32)(k2v >> 32) >= Cstar) { u32 p = atomicAdd(&scount, 1u); if (p < 2048) skey[p] = ~k2v; }
    if (j3 < NANCH && (u32)(k3v >> 32) >= Cstar) { u32 p = atomicAdd(&scount, 1u); if (p < 2048) skey[p] = ~k3v; }
  }
  __syncthreads();
  // ---- bitonic sort 2048 (ascending on ~key == descending key) ----
  for (u32 kk = 2; kk <= 2048; kk <<= 1) {
    for (u32 j = kk >> 1; j > 0; j >>= 1) {
      for (int idx = tid; idx < 2048; idx += 1024) {
        u32 ixj = (u32)idx ^ j;
        if (ixj > (u32)idx) {
          u64 a = skey[idx], c2 = skey[ixj];
          bool up = ((idx & kk) == 0);
          if (up ? (a > c2) : (a < c2)) { skey[idx] = c2; skey[ixj] = a; }
        }
      }
      __syncthreads();
    }
  }
  // ---- epilogue: gather + xywh2xyxy + class-offset boxes ----
  if (tid < MAXC) {
    u64 k = ~skey[tid];
    u32 hi = (u32)(k >> 32);
    u32 lo = (u32)k;
    u32 n = 32767u - (lo >> 7);
    u32 ci = lo & 127u;
    bool valid = hi > 0x80000000u;
    float conf = valid ? __uint_as_float(hi & 0x7FFFFFFFu) : 0.0f;
    const float* pr = pred + ((size_t)b * NANCH + n) * ROWF;
    float x = pr[0], y = pr[1], w = pr[2], h2 = pr[3];
    float x1 = x - w * 0.5f, y1 = y - h2 * 0.5f;
    float x2 = x + w * 0.5f, y2 = y + h2 * 0.5f;
    float cf = (float)ci;
    float off = cf * 4096.0f;
    int o = b * MAXC + tid;
    ((float4*)selbox)[o] = make_float4(x1, y1, x2, y2);
    ((float4*)offbox)[o] = make_float4(x1 + off, y1 + off, x2 + off, y2 + off);
    selconf[o] = conf;
    selcls[o] = cf;
    selvalid[o] = valid ? 1u : 0u;
  }
}

// K3: transposed suppression bits, stored WORD-MAJOR dt[b][w][i] so K4's
// 16-block load is coalesced (k3's 16-lane scatter is absorbed by its 16k
// waves of parallelism).
__global__ __launch_bounds__(256) void k3_dt(const float4* __restrict__ offbox4,
                                             u64* __restrict__ dt) {
  int wid = blockIdx.x * 4 + (threadIdx.x >> 6);   // b*MAXC + i
  int lane = threadIdx.x & 63;
  int b = wid / MAXC;
  int i = wid % MAXC;
  float4 bi = offbox4[b * MAXC + i];
  u64 myword = 0;
  for (int w = 0; w < 16; ++w) {
    int j = w * 64 + lane;
    int jc = (j < MAXC) ? j : 0;
    float4 bj = offbox4[b * MAXC + jc];
    float iou = iou_ref(bi, bj);
    bool bit = (iou > IOU_T) && (j < i);            // j<i implies j<MAXC
    u64 bal = __ballot(bit ? 1 : 0);
    if (lane == w) myword = bal;
  }
  if (lane < 16) dt[((size_t)b * 16 + lane) * MAXC + i] = myword;
}

// K4: Jacobi fixed-point of keep[i] = valid[i] & ~OR_{j<i}(keep[j]&D[j,i]).
// Unique fixed point == greedy NMS; converges in max-chain-depth passes.
__global__ __launch_bounds__(1024) void k4_jacobi(const u64* __restrict__ dt,
                                                  const u32* __restrict__ selvalid,
                                                  const float* __restrict__ selbox,
                                                  const float* __restrict__ selconf,
                                                  const float* __restrict__ selcls,
                                                  float* __restrict__ out) {
  int b = blockIdx.x;
  int tid = threadIdx.x;
  int wv = tid >> 6, lane = tid & 63;
  __shared__ u64 keepv[16];
  __shared__ u32 changed;
  bool valid = false;
  u64 dtr[16];
  if (tid < MAXC) {
    valid = selvalid[b * MAXC + tid] != 0u;
#pragma unroll
    for (int w = 0; w < 16; ++w) dtr[w] = dt[((size_t)b * 16 + w) * MAXC + tid];
  } else {
#pragma unroll
    for (int w = 0; w < 16; ++w) dtr[w] = 0ull;
  }
  u64 bal0 = __ballot(valid ? 1 : 0);
  if (tid == 0) changed = 0;
  if (lane == 0) keepv[wv] = bal0;
  __syncthreads();
  for (int pass = 0; pass < MAXC; ++pass) {
    u64 kv[16];
#pragma unroll
    for (int w = 0; w < 16; ++w) kv[w] = keepv[w];
    u64 s = 0;
#pragma unroll
    for (int w = 0; w < 16; ++w) s |= dtr[w] & kv[w];
    bool nk = valid && (s == 0ull);
    u64 bal = __ballot(nk ? 1 : 0);
    __syncthreads();                       // A: all keepv reads done
    if (lane == 0 && bal != kv[wv]) { keepv[wv] = bal; atomicOr(&changed, 1u); }
    __syncthreads();                       // B: writes visible
    u32 ch = changed;
    __syncthreads();                       // C: all read ch before reset
    if (tid == 0) changed = 0;
    if (!ch) break;                        // ch uniform -> uniform exit
  }
  if (tid < MAXC) {
    bool kept = ((keepv[wv] >> lane) & 1ull) != 0ull;
    size_t o = (size_t)b * MAXC + tid;
    const float4* sb4 = (const float4*)selbox;
    float4 bx = sb4[o];
    float cf = selconf[o], cl = selcls[o];
    float* orow = out + o * 6;
    orow[0] = kept ? bx.x : 0.0f;
    orow[1] = kept ? bx.y : 0.0f;
    orow[2] = kept ? bx.z : 0.0f;
    orow[3] = kept ? bx.w : 0.0f;
    orow[4] = kept ? cf : 0.0f;
    orow[5] = kept ? cl : 0.0f;
    out[(size_t)BATCH * MAXC * 6 + o] = kept ? 1.0f : 0.0f;
  }
}

extern "C" void kernel_launch(void* const* d_in, const int* in_sizes, int n_in,
                              void* d_out, int out_size, void* d_ws, size_t ws_size,
                              hipStream_t stream) {
  const float* pred = (const float*)d_in[0];
  float* out = (float*)d_out;
  char* ws = (char*)d_ws;
  size_t off = 0;
  auto alloc = [&](size_t bytes) -> void* {
    void* p = ws + off;
    off = (off + bytes + 255) & ~(size_t)255;
    return p;
  };
  u64* keys     = (u64*)alloc((size_t)BATCH * NANCH * 8);
  u32* hist     = (u32*)alloc((size_t)BATCH * 256 * 4);
  float* selbox = (float*)alloc((size_t)BATCH * MAXC * 4 * 4);
  float* offbox = (float*)alloc((size_t)BATCH * MAXC * 4 * 4);
  float* selconf= (float*)alloc((size_t)BATCH * MAXC * 4);
  float* selcls = (float*)alloc((size_t)BATCH * MAXC * 4);
  u32* selvalid = (u32*)alloc((size_t)BATCH * MAXC * 4);
  u64* dt       = (u64*)alloc(((size_t)BATCH * 16 * MAXC + 1024) * 8);
  (void)ws_size; (void)in_sizes; (void)n_in; (void)out_size;

  hipMemsetAsync(hist, 0, (size_t)BATCH * 256 * 4, stream);

  dim3 g1(NTILES, BATCH);
  k1_score<<<g1, 256, 0, stream>>>(pred, keys, hist);
  k2_select<<<BATCH, 1024, 0, stream>>>(pred, keys, hist, selbox, offbox,
                                        selconf, selcls, selvalid);
  k3_dt<<<(BATCH * MAXC) / 4, 256, 0, stream>>>((const float4*)offbox, dt);
  k4_jacobi<<<BATCH, 1024, 0, stream>>>(dt, selvalid, selbox, selconf,
                                        selcls, out);
}